// Round 14
// baseline (405.691 us; speedup 1.0000x reference)
//
#include <hip/hip_runtime.h>
#include <hip/hip_fp16.h>

#define T_LEN   262144
#define NV      20
#define NE      30
#define NH      40
#define CHA     128                    // rows per chain; block = 2 chains = 256 rows
#define WARM    64
#define SPC     (WARM + CHA)           // 192 steps per chain
#define NBLK    (T_LEN / (2 * CHA))    // 1024
#define SS      32                     // steps per super-step
#define NSS     (SPC / SS)             // 6
#define WUSS    (WARM / SS)            // 2
#define NTHR    128
#define NW4     1600                   // uint4 count: W_hh packs
#define NW4L    200                    // uint4 count: W_l packs

typedef unsigned u32x2  __attribute__((ext_vector_type(2)));

__device__ __forceinline__ float sig_(float x) {
    x = fminf(fmaxf(x, -30.f), 30.f);
    return __fdividef(1.f, 1.f + __expf(-x));
}
__device__ __forceinline__ float tanh_(float x) {
    x = fminf(fmaxf(x, -15.f), 15.f);
    float e = __expf(2.f * x);
    return __fdividef(e - 1.f, e + 1.f);
}
__device__ __forceinline__ unsigned pkf_(float a, float b) {
    unsigned lo = (unsigned)__half_as_ushort(__float2half(a));
    unsigned hi = (unsigned)__half_as_ushort(__float2half(b));
    return lo | (hi << 16);
}
__device__ __forceinline__ float lo16f_(unsigned u) {
    return __half2float(__ushort_as_half((unsigned short)(u & 0xffffu)));
}
__device__ __forceinline__ float hi16f_(unsigned u) {
    return __half2float(__ushort_as_half((unsigned short)(u >> 16)));
}
// Opaque 16B load: asm-produced values cannot be rematerialized.
__device__ __forceinline__ uint4 gload16_(const uint4* p) {
    uint4 r;
    asm volatile("global_load_dwordx4 %0, %1, off\n\ts_waitcnt vmcnt(0)"
                 : "=v"(r) : "v"(p) : "memory");
    return r;
}

#define D20(V) unsigned V##0,V##1,V##2,V##3,V##4,V##5,V##6,V##7,V##8,V##9, \
    V##10,V##11,V##12,V##13,V##14,V##15,V##16,V##17,V##18,V##19
#define A20(V, C0, C1, C2, C3, C4) do { \
    V##0 =C0.x; V##1 =C0.y; V##2 =C0.z; V##3 =C0.w; \
    V##4 =C1.x; V##5 =C1.y; V##6 =C1.z; V##7 =C1.w; \
    V##8 =C2.x; V##9 =C2.y; V##10=C2.z; V##11=C2.w; \
    V##12=C3.x; V##13=C3.y; V##14=C3.z; V##15=C3.w; \
    V##16=C4.x; V##17=C4.y; V##18=C4.z; V##19=C4.w; } while(0)
#define Z20(V) do { V##0=V##1=V##2=V##3=V##4=V##5=V##6=V##7=V##8=V##9=0u; \
    V##10=V##11=V##12=V##13=V##14=V##15=V##16=V##17=V##18=V##19=0u; } while(0)

#define H2(u) __builtin_bit_cast(__half2, (unsigned)(u))

// Two independent chains (A,B) share the same weight word w##M: 2 readlanes +
// 8 v_pk_fma_f16 per M. Independent dep chains interleave -> latency hiding
// WITHIN one wave (the whole point of this round).
#define ACC2(M) do { \
    unsigned _pA = (unsigned)__builtin_amdgcn_readlane(hpA, 2*(M)); \
    unsigned _pB = (unsigned)__builtin_amdgcn_readlane(hpB, 2*(M)); \
    aI = __hfma2(H2(_pA), H2(w##M),  aI);  bI = __hfma2(H2(_pB), H2(w##M),  bI); \
    aF = __hfma2(H2(_pA), H2(wf##M), aF);  bF = __hfma2(H2(_pB), H2(wf##M), bF); \
    aG = __hfma2(H2(_pA), H2(wg##M), aG);  bG = __hfma2(H2(_pB), H2(wg##M), bG); \
    aO = __hfma2(H2(_pA), H2(wo##M), aO);  bO = __hfma2(H2(_pB), H2(wo##M), bO); \
} while(0)

// ---- prep kernel: pack weights as f16 pairs into d_ws ----
extern "C" __global__ void prep_kernel(const float* __restrict__ W_hh1,
                                       const float* __restrict__ W_hh2,
                                       const float* __restrict__ W_l1,
                                       const float* __restrict__ W_l2,
                                       uint4* __restrict__ ws)
{
    int tid = blockIdx.x * blockDim.x + threadIdx.x;
    for (int p = tid; p < NW4 + NW4L; p += blockDim.x * gridDim.x) {
        uint4 o;
        if (p < NW4) {
            int k = p % NH, r = p / NH;
            int m4 = r % 5;  r /= 5;
            int g  = r % 4;
            int dd = r / 4;
            const float* W = dd ? W_hh2 : W_hh1;
            const float* row = W + (g * NH + k) * NH + 8 * m4;
            o.x = pkf_(row[0], row[1]); o.y = pkf_(row[2], row[3]);
            o.z = pkf_(row[4], row[5]); o.w = pkf_(row[6], row[7]);
        } else {
            int q = p - NW4;
            int v = q % NV, r = q / NV;
            int m4 = r % 5;
            int dd = r / 5;
            const float* W = dd ? W_l2 : W_l1;
            const float* row = W + v * NH + 8 * m4;
            o.x = pkf_(row[0], row[1]); o.y = pkf_(row[2], row[3]);
            o.z = pkf_(row[4], row[5]); o.w = pkf_(row[6], row[7]);
        }
        ws[p] = o;
    }
}

// Blocks: 128 thr = 2 waves = 2 directions; each wave runs TWO independent
// 128-row chains (A,B) in lockstep (shared weight regs, interleaved dep
// chains). Lanes 0-39 = LSTM units, 40-59 = logit riders. f16 u-ring depth
// 128 (&127), both waves store (wave w -> chain w). Block-0 chain A state
// is zero-reset at ss==WUSS (s=64 <=> t=0) for exactness.
extern "C" __global__ void
__attribute__((amdgpu_waves_per_eu(1, 2), amdgpu_flat_work_group_size(NTHR, NTHR)))
bilstm_kernel(const int* __restrict__ tokens,
              const float* __restrict__ embed,
              const float* __restrict__ W_ih1,
              const float* __restrict__ b_ih1, const float* __restrict__ b_hh1,
              const float* __restrict__ W_ih2,
              const float* __restrict__ b_ih2, const float* __restrict__ b_hh2,
              const float* __restrict__ b_l1,  const float* __restrict__ b_l2,
              const uint4* __restrict__ wpk,
              float* __restrict__ out)
{
    __shared__ __align__(16) u32x2 xtab[2][NV][NH];            // f16-pair x-pre
    __shared__ __align__(16) unsigned short uring[2][2][128][NV]; // [chain][dir][slot][v] f16
    __shared__ __align__(16) float embS[NV * NE];
    __shared__ float biasS[NV];
    __shared__ int   tokS[2][2][SPC];                          // [chain][dir][step]

    const int tid  = threadIdx.x;
    const int wave = tid >> 6;          // == direction
    const int lane = tid & 63;
    const int dir  = wave;
    const int a    = blockIdx.x * (2 * CHA);

    // ---- stage embed + tokens + bias ----
    for (int p = tid; p < NV * NE; p += NTHR) embS[p] = embed[p];
    for (int m = tid; m < 2 * 2 * SPC; m += NTHR) {
        int p = m % SPC, r = m / SPC;
        int d = r & 1, q = r >> 1;
        int t = a + q * CHA - WARM + p;
        int tk = 0;
        if (t >= 0) tk = d ? tokens[T_LEN - 1 - t] : tokens[t];
        tokS[q][d][p] = tk;             // t<0 -> placeholder 0 (chain reset later)
    }
    if (tid < NV) biasS[tid] = b_l1[tid] + b_l2[tid];
    __syncthreads();

    // ---- build x-pre table (f16 pairs): xtab[d][v][k] = {(xi,xf),(xg,xo)} ----
    for (int p = tid; p < 2 * NV * NH; p += NTHR) {
        int k = p % NH, q = p / NH;
        int v = q % NV, dd = q / NV;
        const float* Wih = dd ? W_ih2 : W_ih1;
        const float* bi  = dd ? b_ih2 : b_ih1;
        const float* bh  = dd ? b_hh2 : b_hh1;
        float x[4];
        #pragma unroll
        for (int g = 0; g < 4; ++g) {
            int j = g * NH + k;
            float acc = bi[j] + bh[j];
            #pragma unroll
            for (int e = 0; e < NE; ++e) acc += embS[v * NE + e] * Wih[j * NE + e];
            x[g] = acc;
        }
        u32x2 pk; pk.x = pkf_(x[0], x[1]); pk.y = pkf_(x[2], x[3]);
        xtab[dd][v][k] = pk;
    }

    // ---- per-lane weights: opaque 16B loads of pre-packed words ----
    const bool isUnit  = (lane < NH);
    const bool isLogit = (lane >= NH) && (lane < NH + NV);
    const int  kli     = isUnit ? lane : NH - 1;    // clamped xtab lane index

    D20(w); D20(wf); D20(wg); D20(wo);
    if (isUnit) {
        const uint4* b0 = wpk + ((dir * 4 + 0) * 5) * NH + lane;
        const uint4* b1 = wpk + ((dir * 4 + 1) * 5) * NH + lane;
        const uint4* b2 = wpk + ((dir * 4 + 2) * 5) * NH + lane;
        const uint4* b3 = wpk + ((dir * 4 + 3) * 5) * NH + lane;
        uint4 c0, c1, c2, c3, c4;
        c0=gload16_(b0); c1=gload16_(b0+NH); c2=gload16_(b0+2*NH); c3=gload16_(b0+3*NH); c4=gload16_(b0+4*NH);
        A20(w,  c0, c1, c2, c3, c4);
        c0=gload16_(b1); c1=gload16_(b1+NH); c2=gload16_(b1+2*NH); c3=gload16_(b1+3*NH); c4=gload16_(b1+4*NH);
        A20(wf, c0, c1, c2, c3, c4);
        c0=gload16_(b2); c1=gload16_(b2+NH); c2=gload16_(b2+2*NH); c3=gload16_(b2+3*NH); c4=gload16_(b2+4*NH);
        A20(wg, c0, c1, c2, c3, c4);
        c0=gload16_(b3); c1=gload16_(b3+NH); c2=gload16_(b3+2*NH); c3=gload16_(b3+3*NH); c4=gload16_(b3+4*NH);
        A20(wo, c0, c1, c2, c3, c4);
    } else {
        int vv = isLogit ? (lane - NH) : 0;
        const uint4* bl = wpk + NW4 + (dir * 5) * NV + vv;
        uint4 c0, c1, c2, c3, c4;
        c0=gload16_(bl); c1=gload16_(bl+NV); c2=gload16_(bl+2*NV); c3=gload16_(bl+3*NV); c4=gload16_(bl+4*NV);
        A20(w, c0, c1, c2, c3, c4);
        Z20(wf); Z20(wg); Z20(wo);
    }
    __syncthreads();   // xtab + tokS ready

    // ---- init both chains + first x prefetch ----
    int   hbA = 0, hbB = 0;
    float cA = 0.f, cB = 0.f;
    u32x2 xvA = xtab[dir][tokS[0][dir][0]][kli];
    u32x2 xvB = xtab[dir][tokS[1][dir][0]][kli];

    // ---- main loop: NSS super-steps of SS + 1-step flush ----
    #pragma unroll 1
    for (int ss = 0; ss <= NSS; ++ss) {
        if (ss == WUSS && a == 0) { hbA = 0; cA = 0.f; }  // block-0 chain A: exact start at t=0
        const int sbase = ss * SS;
        const int nsl   = (ss < NSS) ? SS : 1;
        #pragma unroll 1
        for (int sl = 0; sl < nsl; ++sl) {
            const int s = sbase + sl;
            unsigned nbA = (unsigned)__builtin_amdgcn_mov_dpp((int)hbA, 0xB1, 0xF, 0xF, true);
            unsigned nbB = (unsigned)__builtin_amdgcn_mov_dpp((int)hbB, 0xB1, 0xF, 0xF, true);
            unsigned hpA = ((unsigned)hbA & 0xffffu) | (nbA << 16);
            unsigned hpB = ((unsigned)hbB & 0xffffu) | (nbB << 16);
            __half2 aI = H2(0u), aF = H2(0u), aG = H2(0u), aO = H2(0u);
            __half2 bI = H2(0u), bF = H2(0u), bG = H2(0u), bO = H2(0u);
            ACC2(0);  ACC2(1);  ACC2(2);  ACC2(3);  ACC2(4);
            ACC2(5);  ACC2(6);  ACC2(7);  ACC2(8);  ACC2(9);
            ACC2(10); ACC2(11); ACC2(12); ACC2(13); ACC2(14);
            ACC2(15); ACC2(16); ACC2(17); ACC2(18); ACC2(19);
            float aiA = __low2float(aI) + __high2float(aI);
            float afA = __low2float(aF) + __high2float(aF);
            float agA = __low2float(aG) + __high2float(aG);
            float aoA = __low2float(aO) + __high2float(aO);
            float aiB = __low2float(bI) + __high2float(bI);
            float afB = __low2float(bF) + __high2float(bF);
            float agB = __low2float(bG) + __high2float(bG);
            float aoB = __low2float(bO) + __high2float(bO);
            if (isUnit) {
                aiA += lo16f_(xvA.x); afA += hi16f_(xvA.x);
                agA += lo16f_(xvA.y); aoA += hi16f_(xvA.y);
                aiB += lo16f_(xvB.x); afB += hi16f_(xvB.x);
                agB += lo16f_(xvB.y); aoB += hi16f_(xvB.y);
            }
            if (isLogit && s >= 1) {                 // u of step s-1
                int us = s - 1;
                uring[0][dir][us & 127][lane - NH] = __half_as_ushort(__float2half(aiA));
                uring[1][dir][us & 127][lane - NH] = __half_as_ushort(__float2half(aiB));
            }
            int sn = (s + 1 < SPC) ? s + 1 : SPC - 1;
            xvA = xtab[dir][tokS[0][dir][sn]][kli];  // prefetch next x
            xvB = xtab[dir][tokS[1][dir][sn]][kli];
            float IA = sig_(aiA), FA = sig_(afA), GA = tanh_(agA), OA = sig_(aoA);
            float IB = sig_(aiB), FB = sig_(afB), GB = tanh_(agB), OB = sig_(aoB);
            cA = fmaf(FA, cA, IA * GA);
            cB = fmaf(FB, cB, IB * GB);
            float hA = OA * tanh_(cA);
            float hB = OB * tanh_(cB);
            hbA = (int)__half_as_ushort(__float2half(hA));
            hbB = (int)__half_as_ushort(__float2half(hB));
        }
        __syncthreads();
        if (ss > WUSS) {                             // store batch B=ss-1 of chain `wave`
            const int B = ss - 1;
            const size_t rbase = (size_t)(a + wave * CHA + B * SS - WARM) * NV;
            #pragma unroll
            for (int i = 0; i < (SS * NV) / 64; ++i) {   // 10
                int e = i * 64 + lane;
                int row = e / NV, v = e - row * NV;
                int slot = (B * SS + row) & 127;
                float sum = __half2float(__ushort_as_half(uring[wave][0][slot][v]))
                          + __half2float(__ushort_as_half(uring[wave][1][slot][v]))
                          + biasS[v];
                out[rbase + e] = sum;
            }
        }
    }
}

extern "C" void kernel_launch(void* const* d_in, const int* in_sizes, int n_in,
                              void* d_out, int out_size, void* d_ws, size_t ws_size,
                              hipStream_t stream)
{
    const int*   tokens = (const int*)  d_in[0];
    const float* embed  = (const float*)d_in[1];
    const float* W_ih1  = (const float*)d_in[2];
    const float* W_hh1  = (const float*)d_in[3];
    const float* b_ih1  = (const float*)d_in[4];
    const float* b_hh1  = (const float*)d_in[5];
    const float* W_ih2  = (const float*)d_in[6];
    const float* W_hh2  = (const float*)d_in[7];
    const float* b_ih2  = (const float*)d_in[8];
    const float* b_hh2  = (const float*)d_in[9];
    const float* W_l1   = (const float*)d_in[10];
    const float* b_l1   = (const float*)d_in[11];
    const float* W_l2   = (const float*)d_in[12];
    const float* b_l2   = (const float*)d_in[13];
    float* outp = (float*)d_out;
    uint4* wpk  = (uint4*)d_ws;

    hipLaunchKernelGGL(prep_kernel, dim3(8), dim3(256), 0, stream,
                       W_hh1, W_hh2, W_l1, W_l2, wpk);
    hipLaunchKernelGGL(bilstm_kernel, dim3(NBLK), dim3(NTHR), 0, stream,
                       tokens, embed, W_ih1, b_ih1, b_hh1,
                       W_ih2, b_ih2, b_hh2, b_l1, b_l2, wpk, outp);
}

// Round 16
// 107.756 us; speedup vs baseline: 3.7649x; 3.7649x over previous
//
#include <hip/hip_runtime.h>
#include <hip/hip_fp16.h>

#define T_LEN   262144
#define NV      20
#define NE      30
#define NH      40
#define NCH     16                     // chains per wave
#define CHA     32                     // output rows per chain
#define WARM    32
#define SPC     (WARM + CHA)           // 64 sequential steps
#define NBLK    (T_LEN / (NCH * CHA))  // 512
#define NTHR    128
#define NFRAG   40                     // B-fragments per direction

typedef _Float16 h8 __attribute__((ext_vector_type(8)));
typedef float    f4 __attribute__((ext_vector_type(4)));

__device__ __forceinline__ float sigf_(float x) {
    float e = __builtin_amdgcn_exp2f(-1.44269504f * x);
    return __builtin_amdgcn_rcpf(1.f + e);
}
__device__ __forceinline__ float tanhf_(float x) {
    float e = __builtin_amdgcn_exp2f(2.88539008f * x);
    return 1.f - 2.f * __builtin_amdgcn_rcpf(e + 1.f);
}

// ---- prep: build B-fragments (f16) for the step-MFMA ----
// Virtual B is 96x224 per direction:
//   K rows: [0,40) h-units | [40,64) zero | [64,84) one-hot vocab -> x-pre | [84,96) zero
//   N cols: 12 gate tiles (gate-major, units padded 40->48: col=gate*48+u) + 2 logit tiles (W_l)
// frag id fi<36: nt=fi/3 (N-tile), kt=fi%3 (K-tile); fi>=36: logit (lt,kt2).
// Frag layout (16x16x32 f16): lane holds col n=lane&15, k-rows (lane>>4)*8+j.
extern "C" __global__ void prep_kernel(const float* __restrict__ embed,
    const float* __restrict__ W_ih1, const float* __restrict__ W_hh1,
    const float* __restrict__ b_ih1, const float* __restrict__ b_hh1,
    const float* __restrict__ W_ih2, const float* __restrict__ W_hh2,
    const float* __restrict__ b_ih2, const float* __restrict__ b_hh2,
    const float* __restrict__ W_l1,  const float* __restrict__ W_l2,
    unsigned short* __restrict__ ws)
{
    int it = blockIdx.x * blockDim.x + threadIdx.x;     // [0, 2*40*64)
    if (it >= 2 * NFRAG * 64) return;
    int lane = it & 63;
    int fi   = (it >> 6) % NFRAG;
    int d    = it / (NFRAG * 64);
    const float* Whh = d ? W_hh2 : W_hh1;
    const float* Wih = d ? W_ih2 : W_ih1;
    const float* bi  = d ? b_ih2 : b_ih1;
    const float* bh  = d ? b_hh2 : b_hh1;
    const float* Wl  = d ? W_l2  : W_l1;
    int n16 = lane & 15, kb = lane >> 4;
    for (int j = 0; j < 8; ++j) {
        float val = 0.f;
        if (fi < 36) {
            int nt = fi / 3, kt = fi % 3;
            int gate = nt / 3, u = (nt % 3) * 16 + n16;
            if (u < NH) {
                int jrow = gate * NH + u;
                if (kt < 2) {
                    int kk = kt * 32 + kb * 8 + j;
                    if (kk < NH) val = Whh[jrow * NH + kk];
                } else {
                    int v = kb * 8 + j;                 // one-hot vocab index
                    if (v < NV) {
                        float acc = bi[jrow] + bh[jrow];
                        for (int e = 0; e < NE; ++e)
                            acc += embed[v * NE + e] * Wih[jrow * NE + e];
                        val = acc;
                    }
                }
            }
        } else {
            int q = fi - 36, lt = q >> 1, kt = q & 1;
            int v = lt * 16 + n16;
            int kk = kt * 32 + kb * 8 + j;
            if (v < NV && kk < NH) val = Wl[v * NH + kk];
        }
        ws[(size_t)it * 8 + j] = __half_as_ushort(__float2half(val));
    }
}

#define MFMA_(A, B, C) __builtin_amdgcn_mfma_f32_16x16x32_f16((A), (B), (C), 0, 0, 0)
#define MM3(NT) ({ f4 _p = {0.f,0.f,0.f,0.f}; \
    _p = MFMA_(A2, B##NT##_2, _p); \
    _p = MFMA_(A1, B##NT##_1, _p); \
    _p = MFMA_(A0, B##NT##_0, _p); _p; })

#define BDECL(NT) h8 B##NT##_0, B##NT##_1, B##NT##_2
#define BLOAD(NT) do { \
    B##NT##_0 = WB[(size_t)(fb + NT*3 + 0) * 64 + lane]; \
    B##NT##_1 = WB[(size_t)(fb + NT*3 + 1) * 64 + lane]; \
    B##NT##_2 = WB[(size_t)(fb + NT*3 + 2) * 64 + lane]; } while (0)

// one (unit-slot JT, chain-row R) cell update from gate preacts
#define CELL(JT, R, PI, PF, PG, PO) do { \
    float I_ = sigf_((PI)[R]); float F_ = sigf_((PF)[R]); \
    float G_ = tanhf_((PG)[R]); float O_ = sigf_((PO)[R]); \
    float c_ = fmaf(F_, cst[JT][R], I_ * G_); \
    cst[JT][R] = c_; \
    float h_ = O_ * tanhf_(c_); \
    int ch_ = kb4 + R; \
    int wa_ = ((ch_ << 7) + ((JT * 16 + n16) << 1)) ^ ((ch_ & 7) << 4); \
    *(_Float16*)((char*)hb + wa_) = (_Float16)h_; \
} while (0)

#define JTB(JT, TI, TF, TG, TO) do { \
    f4 pI = MM3(TI); f4 pF = MM3(TF); f4 pG = MM3(TG); f4 pO = MM3(TO); \
    CELL(JT, 0, pI, pF, pG, pO); CELL(JT, 1, pI, pF, pG, pO); \
    CELL(JT, 2, pI, pF, pG, pO); CELL(JT, 3, pI, pF, pG, pO); \
} while (0)

// Block = 2 waves: wave0 = fwd, wave1 = bwd; each wave steps 16 chains via MFMA.
// Per iteration s: A0/A1 = h_{s-1} (read BEFORE update). Logits from A0/A1
// therefore belong to output step s-1 (R15's bug: stored them at s). Loop runs
// one extra flush iteration s=SPC for the last row. 1 barrier per tail iter.
extern "C" __global__ void
__attribute__((amdgpu_waves_per_eu(1, 1), amdgpu_flat_work_group_size(NTHR, NTHR)))
bilstm_kernel(const int* __restrict__ tokens,
              const float* __restrict__ b_l1, const float* __restrict__ b_l2,
              const unsigned short* __restrict__ wpk,
              float* __restrict__ out)
{
    __shared__ _Float16 hbuf[2][NCH][64];      // [dir][chain][k-col], swizzled
    __shared__ float    ubuf[2][NCH][32];      // [parity][chain][v]
    __shared__ int      tokS[2][SPC][NCH];

    const int tid  = threadIdx.x;
    const int dir  = tid >> 6;
    const int lane = tid & 63;
    const int n16  = lane & 15;
    const int kb   = lane >> 4;
    const int kb4  = kb << 2;
    const long rowbase = (long)blockIdx.x * (NCH * CHA);

    // ---- stage tokens (clamped at t<0; chain 0 of block 0 resets at t==0) ----
    for (int m = tid; m < 2 * SPC * NCH; m += NTHR) {
        int ch = m & 15, s = (m >> 4) % SPC, d = m / (SPC * NCH);
        long t = rowbase + ch * CHA - WARM + s;
        int ti = t < 0 ? 0 : (int)t;
        tokS[d][s][ch] = d ? tokens[T_LEN - 1 - ti] : tokens[ti];
    }
    // ---- zero h buffers ----
    for (int m = tid; m < 2 * NCH * 64; m += NTHR)
        ((unsigned short*)hbuf)[m] = 0;
    __syncthreads();

    // ---- load 40 B-fragments (resident; waves_per_eu(1,1) -> 512-reg budget) ----
    const h8* WB = (const h8*)wpk;
    const int fb = dir * NFRAG;
    BDECL(0); BDECL(1); BDECL(2); BDECL(3); BDECL(4);  BDECL(5);
    BDECL(6); BDECL(7); BDECL(8); BDECL(9); BDECL(10); BDECL(11);
    BLOAD(0); BLOAD(1); BLOAD(2); BLOAD(3); BLOAD(4);  BLOAD(5);
    BLOAD(6); BLOAD(7); BLOAD(8); BLOAD(9); BLOAD(10); BLOAD(11);
    h8 L0_0 = WB[(size_t)(fb + 36) * 64 + lane];
    h8 L0_1 = WB[(size_t)(fb + 37) * 64 + lane];
    h8 L1_0 = WB[(size_t)(fb + 38) * 64 + lane];
    h8 L1_1 = WB[(size_t)(fb + 39) * 64 + lane];

    // ---- per-lane state: 3 unit-slots x 4 chain-rows ----
    float cst[3][4] = {{0.f,0.f,0.f,0.f},{0.f,0.f,0.f,0.f},{0.f,0.f,0.f,0.f}};
    _Float16* hb = &hbuf[dir][0][0];

    float bias0 = b_l1[n16] + b_l2[n16];
    int   v1i   = 16 + n16;
    float bias1 = (v1i < NV) ? (b_l1[v1i] + b_l2[v1i]) : 0.f;

    // A-read addresses (row = n16 chain, cols kb*8..+7 and +32), swizzled
    const int a0s = ((n16 << 7) + (kb << 4)) ^ ((n16 & 7) << 4);
    const int a1s = ((n16 << 7) + (kb << 4) + 64) ^ ((n16 & 7) << 4);

    #pragma unroll 1
    for (int s = 0; s <= SPC; ++s) {
        // ---- A fragments: h state AFTER iteration s-1 ----
        h8 A0 = *(const h8*)((char*)hb + a0s);
        h8 A1 = *(const h8*)((char*)hb + a1s);

        // ---- logits for output step s-1 (uses h_{s-1}) ----
        if (s >= WARM + 1) {
            f4 u0 = {0.f,0.f,0.f,0.f};
            u0 = MFMA_(A1, L0_1, u0); u0 = MFMA_(A0, L0_0, u0);
            f4 u1 = {0.f,0.f,0.f,0.f};
            u1 = MFMA_(A1, L1_1, u1); u1 = MFMA_(A0, L1_0, u1);
            const int par = s & 1;
            if (dir == 0) {
                #pragma unroll
                for (int r = 0; r < 4; ++r) {
                    ubuf[par][kb4 + r][n16]      = u0[r];
                    ubuf[par][kb4 + r][16 + n16] = u1[r];
                }
            }
            __syncthreads();
            if (dir == 1) {
                #pragma unroll
                for (int r = 0; r < 4; ++r) {
                    int ch = kb4 + r;
                    long t = rowbase + ch * CHA + (s - 1 - WARM);
                    float o0 = u0[r] + ubuf[par][ch][n16] + bias0;
                    out[t * NV + n16] = o0;
                    if (v1i < NV) {
                        float o1 = u1[r] + ubuf[par][ch][16 + n16] + bias1;
                        out[t * NV + v1i] = o1;
                    }
                }
            }
        }

        if (s < SPC) {
            // ---- one-hot token fragment ----
            int tok = tokS[dir][s][n16];
            h8 A2 = (h8)(_Float16)0;
            {
                int rel = tok - (kb << 3);
                A2[0] = (rel == 0) ? (_Float16)1 : (_Float16)0;
                A2[1] = (rel == 1) ? (_Float16)1 : (_Float16)0;
                A2[2] = (rel == 2) ? (_Float16)1 : (_Float16)0;
                A2[3] = (rel == 3) ? (_Float16)1 : (_Float16)0;
                A2[4] = (rel == 4) ? (_Float16)1 : (_Float16)0;
                A2[5] = (rel == 5) ? (_Float16)1 : (_Float16)0;
                A2[6] = (rel == 6) ? (_Float16)1 : (_Float16)0;
                A2[7] = (rel == 7) ? (_Float16)1 : (_Float16)0;
            }

            // ---- gates + cell update (unit-slot jt: i=jt, f=3+jt, g=6+jt, o=9+jt) ----
            JTB(0, 0, 3, 6, 9);
            JTB(1, 1, 4, 7, 10);
            JTB(2, 2, 5, 8, 11);

            // ---- exact start for chain 0 of block 0 (t==0 at s==WARM) ----
            if (blockIdx.x == 0 && s == WARM - 1) {
                if (lane < 16) { cst[0][0] = 0.f; cst[1][0] = 0.f; cst[2][0] = 0.f; }
                hb[lane] = (_Float16)0;        // zero hbuf row 0 (chain 0; row-0 swizzle = 0)
            }
        }
    }
}

extern "C" void kernel_launch(void* const* d_in, const int* in_sizes, int n_in,
                              void* d_out, int out_size, void* d_ws, size_t ws_size,
                              hipStream_t stream)
{
    const int*   tokens = (const int*)  d_in[0];
    const float* embed  = (const float*)d_in[1];
    const float* W_ih1  = (const float*)d_in[2];
    const float* W_hh1  = (const float*)d_in[3];
    const float* b_ih1  = (const float*)d_in[4];
    const float* b_hh1  = (const float*)d_in[5];
    const float* W_ih2  = (const float*)d_in[6];
    const float* W_hh2  = (const float*)d_in[7];
    const float* b_ih2  = (const float*)d_in[8];
    const float* b_hh2  = (const float*)d_in[9];
    const float* W_l1   = (const float*)d_in[10];
    const float* b_l1   = (const float*)d_in[11];
    const float* W_l2   = (const float*)d_in[12];
    const float* b_l2   = (const float*)d_in[13];
    float* outp = (float*)d_out;
    unsigned short* wpk = (unsigned short*)d_ws;

    hipLaunchKernelGGL(prep_kernel, dim3(20), dim3(256), 0, stream,
                       embed, W_ih1, W_hh1, b_ih1, b_hh1,
                       W_ih2, W_hh2, b_ih2, b_hh2, W_l1, W_l2, wpk);
    hipLaunchKernelGGL(bilstm_kernel, dim3(NBLK), dim3(NTHR), 0, stream,
                       tokens, b_l1, b_l2, wpk, outp);
}